// Round 1
// baseline (492.246 us; speedup 1.0000x reference)
//
#include <hip/hip_runtime.h>
#include <math.h>

#define NR 8192
#define DIM 1024

typedef __attribute__((ext_vector_type(8))) short bf16x8;
typedef __attribute__((ext_vector_type(4))) float f32x4;

static __device__ __forceinline__ unsigned short f2bf(float f) {
  unsigned int u = __float_as_uint(f);
  u += 0x7fffu + ((u >> 16) & 1u);   // round-to-nearest-even
  return (unsigned short)(u >> 16);
}

static __device__ __forceinline__ void gload_lds16(const void* g, void* lds) {
  __builtin_amdgcn_global_load_lds(
      (const __attribute__((address_space(1))) unsigned int*)g,
      (__attribute__((address_space(3))) unsigned int*)lds, 16, 0, 0);
}

// ---------------- fp32 -> bf16 convert (vectorized) ----------------
__global__ __launch_bounds__(256) void cvt_bf16(const float* __restrict__ in,
                                                unsigned short* __restrict__ outp,
                                                int n4) {
  int i = blockIdx.x * 256 + threadIdx.x;
  if (i < n4) {
    float4 v = ((const float4*)in)[i];
    ushort4 o;
    o.x = f2bf(v.x); o.y = f2bf(v.y); o.z = f2bf(v.z); o.w = f2bf(v.w);
    ((ushort4*)outp)[i] = o;
  }
}

// ---------------- shared 128x128 bf16 NT GEMM core (m97 structure) ----------------
// A[M][K] row-major bf16, B[N][K] row-major bf16 (i.e. computes A * B^T).
// acc[m][n] fragment (16x16x32), wave grid 2x2, each wave owns 64x64.
static __device__ __forceinline__ void gemm_core(const unsigned short* A,
                                                 const unsigned short* B,
                                                 int m0, int n0, int K,
                                                 short* As, short* Bs,
                                                 f32x4 acc[4][4]) {
  const int tid  = threadIdx.x;
  const int lane = tid & 63;
  const int wave = tid >> 6;
  const int wr = wave >> 1, wc = wave & 1;
  const int ch_r = lane >> 2;        // row within a 16-row staging chunk
  const int ch_c = (lane & 3) * 8;   // bf16-element k offset within row

  for (int kt = 0; kt < K; kt += 32) {
    // stage A(128x32) + B(128x32) into LDS: 16 wave-calls of 1KB, 4 per wave
#pragma unroll
    for (int c = 0; c < 4; ++c) {
      int ch = wave * 4 + c;
      if (ch < 8) {
        const unsigned short* g = A + (size_t)(m0 + ch * 16 + ch_r) * DIM + kt + ch_c;
        gload_lds16(g, As + ch * 512);
      } else {
        const unsigned short* g = B + (size_t)(n0 + (ch - 8) * 16 + ch_r) * DIM + kt + ch_c;
        gload_lds16(g, Bs + (ch - 8) * 512);
      }
    }
    asm volatile("s_waitcnt vmcnt(0)" ::: "memory");
    __syncthreads();

    bf16x8 af[4], bfr[4];
#pragma unroll
    for (int m = 0; m < 4; ++m)
      af[m] = *(const bf16x8*)(As + (wr * 64 + m * 16 + (lane & 15)) * 32 + (lane >> 4) * 8);
#pragma unroll
    for (int n = 0; n < 4; ++n)
      bfr[n] = *(const bf16x8*)(Bs + (wc * 64 + n * 16 + (lane & 15)) * 32 + (lane >> 4) * 8);
#pragma unroll
    for (int m = 0; m < 4; ++m)
#pragma unroll
      for (int n = 0; n < 4; ++n)
        acc[m][n] = __builtin_amdgcn_mfma_f32_16x16x32_bf16(af[m], bfr[n], acc[m][n], 0, 0, 0);
    __syncthreads();
  }
}

// ---------------- GEMM1: xp = relu(x @ W^T + b), bf16 out ----------------
__global__ __launch_bounds__(256) void gemm1_relu(const unsigned short* __restrict__ Xb,
                                                  const unsigned short* __restrict__ Wb,
                                                  const float* __restrict__ bias,
                                                  unsigned short* __restrict__ XP) {
  __shared__ short As[4096], Bs[4096];
  const int m0 = blockIdx.y * 128, n0 = blockIdx.x * 128;
  f32x4 acc[4][4] = {};
  gemm_core(Xb, Wb, m0, n0, DIM, As, Bs, acc);

  const int lane = threadIdx.x & 63, wave = threadIdx.x >> 6;
  const int wr = wave >> 1, wc = wave & 1, g = lane >> 4, li = lane & 15;
#pragma unroll
  for (int m = 0; m < 4; ++m)
#pragma unroll
    for (int n = 0; n < 4; ++n) {
      int col = n0 + wc * 64 + n * 16 + li;
      float bv = bias[col];
#pragma unroll
      for (int r = 0; r < 4; ++r) {
        int row = m0 + wr * 64 + m * 16 + g * 4 + r;
        float v = fmaxf(acc[m][n][r] + bv, 0.0f);
        XP[(size_t)row * DIM + col] = f2bf(v);
      }
    }
}

// ---------------- GEMM2: scores tile + mask + recency + flash partials ----------------
__global__ __launch_bounds__(256) void gemm2_scores(const unsigned short* __restrict__ XP,
                                                    const float* __restrict__ rwp,
                                                    float* __restrict__ out,
                                                    float* __restrict__ wsm,
                                                    float* __restrict__ wsl) {
  const int bx = blockIdx.x, by = blockIdx.y;
  if (bx > by) return;  // strictly-upper tiles fully masked; normalize kernel writes zeros
  __shared__ short As[4096], Bs[4096];
  const int m0 = by * 128, n0 = bx * 128;
  f32x4 acc[4][4] = {};
  gemm_core(XP, XP, m0, n0, DIM, As, Bs, acc);

  const float rw = rwp[0];
  const int lane = threadIdx.x & 63, wave = threadIdx.x >> 6;
  const int wr = wave >> 1, wc = wave & 1, g = lane >> 4, li = lane & 15;
  const int pcol = bx * 2 + wc;  // 64-col chunk index

#pragma unroll
  for (int m = 0; m < 4; ++m) {
#pragma unroll
    for (int r = 0; r < 4; ++r) {
      const int row = m0 + wr * 64 + m * 16 + g * 4 + r;
      float s[4];
      float mx = -INFINITY;
#pragma unroll
      for (int n = 0; n < 4; ++n) {
        int col = n0 + wc * 64 + n * 16 + li;
        float v = acc[m][n][r];
        if (col <= row) {
          v += rw * (float)(row - col);          // recency bias (rw = -0.5)
          out[(size_t)row * NR + col] = v;       // raw score, re-read by normalize
        } else {
          v = -INFINITY;                         // causal mask
        }
        s[n] = v;
        mx = fmaxf(mx, v);
      }
      // row-chunk max over the 16 lanes holding this row
#pragma unroll
      for (int off = 1; off < 16; off <<= 1) mx = fmaxf(mx, __shfl_xor(mx, off));
      float se = 0.0f;
#pragma unroll
      for (int n = 0; n < 4; ++n) se += __expf(s[n] - mx);
#pragma unroll
      for (int off = 1; off < 16; off <<= 1) se += __shfl_xor(se, off);
      if (li == 0) {
        // NaN possible only when the whole 64-col chunk is masked (pcol > row/64);
        // those slots are never read by rowstats.
        wsm[(size_t)row * 128 + pcol] = mx;
        wsl[(size_t)row * 128 + pcol] = se;
      }
    }
  }
}

// ---------------- per-row reduction of flash partials ----------------
__global__ __launch_bounds__(256) void rowstats(const float* __restrict__ wsm,
                                                const float* __restrict__ wsl,
                                                float* __restrict__ Ms,
                                                float* __restrict__ Ls) {
  const int row = blockIdx.x * 4 + (threadIdx.x >> 6);
  const int lane = threadIdx.x & 63;
  const int nch = (row >> 6) + 1;  // valid 64-col chunks for this row
  float m0v = (lane < nch) ? wsm[(size_t)row * 128 + lane] : -INFINITY;
  float m1v = (lane + 64 < nch) ? wsm[(size_t)row * 128 + lane + 64] : -INFINITY;
  float mx = fmaxf(m0v, m1v);
#pragma unroll
  for (int off = 1; off < 64; off <<= 1) mx = fmaxf(mx, __shfl_xor(mx, off));
  float l = 0.0f;
  if (lane < nch)      l += wsl[(size_t)row * 128 + lane]      * __expf(m0v - mx);
  if (lane + 64 < nch) l += wsl[(size_t)row * 128 + lane + 64] * __expf(m1v - mx);
#pragma unroll
  for (int off = 1; off < 64; off <<= 1) l += __shfl_xor(l, off);
  if (lane == 0) { Ms[row] = mx; Ls[row] = 1.0f / l; }
}

// ---------------- normalize: out = exp(s - M) * invL (lower), 0 (upper) ----------------
__global__ __launch_bounds__(256) void normk(float* __restrict__ out,
                                             const float* __restrict__ Ms,
                                             const float* __restrict__ Ls) {
  const size_t idx = (size_t)blockIdx.x * 256 + threadIdx.x;  // float4 index
  const int row = (int)(idx >> 11);      // 2048 float4 per row
  const int j0 = (int)(idx & 2047) * 4;
  float4* p = (float4*)out + idx;
  const float M = Ms[row], sc = Ls[row];
  if (j0 + 3 <= row) {
    float4 v = *p;
    v.x = __expf(v.x - M) * sc;
    v.y = __expf(v.y - M) * sc;
    v.z = __expf(v.z - M) * sc;
    v.w = __expf(v.w - M) * sc;
    *p = v;
  } else if (j0 > row) {
    float4 z; z.x = 0.f; z.y = 0.f; z.z = 0.f; z.w = 0.f;
    *p = z;
  } else {
    float4 v = *p;  // boundary quad; masked bytes are poison but unused
    float4 o;
    o.x = (j0 + 0 <= row) ? __expf(v.x - M) * sc : 0.f;
    o.y = (j0 + 1 <= row) ? __expf(v.y - M) * sc : 0.f;
    o.z = (j0 + 2 <= row) ? __expf(v.z - M) * sc : 0.f;
    o.w = (j0 + 3 <= row) ? __expf(v.w - M) * sc : 0.f;
    *p = o;
  }
}

extern "C" void kernel_launch(void* const* d_in, const int* in_sizes, int n_in,
                              void* d_out, int out_size, void* d_ws, size_t ws_size,
                              hipStream_t stream) {
  const float* x  = (const float*)d_in[0];
  const float* W  = (const float*)d_in[1];
  const float* b  = (const float*)d_in[2];
  const float* rw = (const float*)d_in[3];
  float* out = (float*)d_out;

  char* ws = (char*)d_ws;
  unsigned short* Xb = (unsigned short*)(ws);                        // 16 MB
  unsigned short* Wb = (unsigned short*)(ws + (size_t)(16 << 20));   //  2 MB
  unsigned short* XP = (unsigned short*)(ws + (size_t)(18 << 20));   // 16 MB
  float* wsm = (float*)(ws + (size_t)(34 << 20));                    //  4 MB
  float* wsl = (float*)(ws + (size_t)(38 << 20));                    //  4 MB
  float* Ms  = (float*)(ws + (size_t)(42 << 20));                    // 32 KB
  float* Ls  = (float*)(ws + (size_t)(42 << 20) + 32768);            // 32 KB

  cvt_bf16<<<NR * DIM / 4 / 256, 256, 0, stream>>>(x, Xb, NR * DIM / 4);
  cvt_bf16<<<DIM * DIM / 4 / 256, 256, 0, stream>>>(W, Wb, DIM * DIM / 4);
  gemm1_relu<<<dim3(DIM / 128, NR / 128), 256, 0, stream>>>(Xb, Wb, b, XP);
  gemm2_scores<<<dim3(NR / 128, NR / 128), 256, 0, stream>>>(XP, rw, out, wsm, wsl);
  rowstats<<<NR / 4, 256, 0, stream>>>(wsm, wsl, Ms, Ls);
  normk<<<(NR / 4) * (NR / 256), 256, 0, stream>>>(out, Ms, Ls);
}

// Round 2
// 453.307 us; speedup vs baseline: 1.0859x; 1.0859x over previous
//
#include <hip/hip_runtime.h>
#include <math.h>

#define NR 8192
#define DIM 1024

typedef __attribute__((ext_vector_type(8))) short bf16x8;
typedef __attribute__((ext_vector_type(4))) float f32x4;

static __device__ __forceinline__ unsigned short f2bf(float f) {
  unsigned int u = __float_as_uint(f);
  u += 0x7fffu + ((u >> 16) & 1u);   // round-to-nearest-even
  return (unsigned short)(u >> 16);
}

static __device__ __forceinline__ float bf2f(unsigned short u) {
  return __uint_as_float(((unsigned int)u) << 16);
}

static __device__ __forceinline__ void gload_lds16(const void* g, void* lds) {
  __builtin_amdgcn_global_load_lds(
      (const __attribute__((address_space(1))) unsigned int*)g,
      (__attribute__((address_space(3))) unsigned int*)lds, 16, 0, 0);
}

// ---------------- fp32 -> bf16 convert (vectorized) ----------------
__global__ __launch_bounds__(256) void cvt_bf16(const float* __restrict__ in,
                                                unsigned short* __restrict__ outp,
                                                int n4) {
  int i = blockIdx.x * 256 + threadIdx.x;
  if (i < n4) {
    float4 v = ((const float4*)in)[i];
    ushort4 o;
    o.x = f2bf(v.x); o.y = f2bf(v.y); o.z = f2bf(v.z); o.w = f2bf(v.w);
    ((ushort4*)outp)[i] = o;
  }
}

// ---------------- shared 128x128 bf16 NT GEMM core (m97 structure) ----------------
// A[M][K] row-major bf16, B[N][K] row-major bf16 (computes A * B^T).
static __device__ __forceinline__ void gemm_core(const unsigned short* A,
                                                 const unsigned short* B,
                                                 int m0, int n0, int K,
                                                 short* As, short* Bs,
                                                 f32x4 acc[4][4]) {
  const int tid  = threadIdx.x;
  const int lane = tid & 63;
  const int wave = tid >> 6;
  const int wr = wave >> 1, wc = wave & 1;
  const int ch_r = lane >> 2;        // row within a 16-row staging chunk
  const int ch_c = (lane & 3) * 8;   // bf16-element k offset within row

  for (int kt = 0; kt < K; kt += 32) {
#pragma unroll
    for (int c = 0; c < 4; ++c) {
      int ch = wave * 4 + c;
      if (ch < 8) {
        const unsigned short* g = A + (size_t)(m0 + ch * 16 + ch_r) * DIM + kt + ch_c;
        gload_lds16(g, As + ch * 512);
      } else {
        const unsigned short* g = B + (size_t)(n0 + (ch - 8) * 16 + ch_r) * DIM + kt + ch_c;
        gload_lds16(g, Bs + (ch - 8) * 512);
      }
    }
    asm volatile("s_waitcnt vmcnt(0)" ::: "memory");
    __syncthreads();

    bf16x8 af[4], bfr[4];
#pragma unroll
    for (int m = 0; m < 4; ++m)
      af[m] = *(const bf16x8*)(As + (wr * 64 + m * 16 + (lane & 15)) * 32 + (lane >> 4) * 8);
#pragma unroll
    for (int n = 0; n < 4; ++n)
      bfr[n] = *(const bf16x8*)(Bs + (wc * 64 + n * 16 + (lane & 15)) * 32 + (lane >> 4) * 8);
#pragma unroll
    for (int m = 0; m < 4; ++m)
#pragma unroll
      for (int n = 0; n < 4; ++n)
        acc[m][n] = __builtin_amdgcn_mfma_f32_16x16x32_bf16(af[m], bfr[n], acc[m][n], 0, 0, 0);
    __syncthreads();
  }
}

// ---------------- GEMM1: xp = relu(x @ W^T + b), bf16 out ----------------
__global__ __launch_bounds__(256) void gemm1_relu(const unsigned short* __restrict__ Xb,
                                                  const unsigned short* __restrict__ Wb,
                                                  const float* __restrict__ bias,
                                                  unsigned short* __restrict__ XP) {
  __shared__ short As[4096], Bs[4096];
  const int m0 = blockIdx.y * 128, n0 = blockIdx.x * 128;
  f32x4 acc[4][4] = {};
  gemm_core(Xb, Wb, m0, n0, DIM, As, Bs, acc);

  const int lane = threadIdx.x & 63, wave = threadIdx.x >> 6;
  const int wr = wave >> 1, wc = wave & 1, g = lane >> 4, li = lane & 15;
#pragma unroll
  for (int m = 0; m < 4; ++m)
#pragma unroll
    for (int n = 0; n < 4; ++n) {
      int col = n0 + wc * 64 + n * 16 + li;
      float bv = bias[col];
#pragma unroll
      for (int r = 0; r < 4; ++r) {
        int row = m0 + wr * 64 + m * 16 + g * 4 + r;
        float v = fmaxf(acc[m][n][r] + bv, 0.0f);
        XP[(size_t)row * DIM + col] = f2bf(v);
      }
    }
}

// ---------------- GEMM2: scores tile + mask + recency + flash partials ----------------
// Packed lower-triangle grid (2080 blocks), XCD-swizzled. Stores P = exp(s - m_chunk)
// as bf16 into Pb; per-(row, 64-col-chunk) partials (m, l) into wsm/wsl.
__global__ __launch_bounds__(256) void gemm2_scores(const unsigned short* __restrict__ XP,
                                                    const float* __restrict__ rwp,
                                                    unsigned short* __restrict__ Pb,
                                                    float* __restrict__ wsm,
                                                    float* __restrict__ wsl) {
  // XCD swizzle: nwg = 2080, 2080 % 8 == 0 -> bijective simple form
  int t = ((int)blockIdx.x & 7) * 260 + ((int)blockIdx.x >> 3);
  // triangular decode: t = by*(by+1)/2 + bx, bx <= by
  int by = (int)((sqrtf(8.0f * (float)t + 1.0f) - 1.0f) * 0.5f);
  while ((by + 1) * (by + 2) / 2 <= t) ++by;
  while (by * (by + 1) / 2 > t) --by;
  const int bx = t - by * (by + 1) / 2;

  __shared__ short As[4096], Bs[4096];
  const int m0 = by * 128, n0 = bx * 128;
  f32x4 acc[4][4] = {};
  gemm_core(XP, XP, m0, n0, DIM, As, Bs, acc);

  const float rw = rwp[0];
  const int lane = threadIdx.x & 63, wave = threadIdx.x >> 6;
  const int wr = wave >> 1, wc = wave & 1, g = lane >> 4, li = lane & 15;
  const int pcol = bx * 2 + wc;  // 64-col chunk index

#pragma unroll
  for (int m = 0; m < 4; ++m) {
#pragma unroll
    for (int r = 0; r < 4; ++r) {
      const int row = m0 + wr * 64 + m * 16 + g * 4 + r;
      float s[4];
      float mx = -INFINITY;
#pragma unroll
      for (int n = 0; n < 4; ++n) {
        int col = n0 + wc * 64 + n * 16 + li;
        float v = acc[m][n][r];
        v = (col <= row) ? v + rw * (float)(row - col) : -INFINITY;
        s[n] = v;
        mx = fmaxf(mx, v);
      }
#pragma unroll
      for (int off = 1; off < 16; off <<= 1) mx = fmaxf(mx, __shfl_xor(mx, off));
      float se = 0.0f;
#pragma unroll
      for (int n = 0; n < 4; ++n) {
        float e = __expf(s[n] - mx);   // masked: exp(-inf - finite) = 0
        se += e;
        int col = n0 + wc * 64 + n * 16 + li;
        if (col <= row) Pb[(size_t)row * NR + col] = f2bf(e);
      }
#pragma unroll
      for (int off = 1; off < 16; off <<= 1) se += __shfl_xor(se, off);
      if (li == 0) {
        // fully-masked chunk (pcol > row>>6) may store NaN; never read by rowstats
        wsm[(size_t)row * 128 + pcol] = mx;
        wsl[(size_t)row * 128 + pcol] = se;
      }
    }
  }
}

// ---------------- per-row reduction of flash partials ----------------
__global__ __launch_bounds__(256) void rowstats(const float* __restrict__ wsm,
                                                const float* __restrict__ wsl,
                                                float* __restrict__ Ms,
                                                float* __restrict__ Ls) {
  const int row = blockIdx.x * 4 + (threadIdx.x >> 6);
  const int lane = threadIdx.x & 63;
  const int nch = (row >> 6) + 1;  // valid 64-col chunks for this row
  float m0v = (lane < nch) ? wsm[(size_t)row * 128 + lane] : -INFINITY;
  float m1v = (lane + 64 < nch) ? wsm[(size_t)row * 128 + lane + 64] : -INFINITY;
  float mx = fmaxf(m0v, m1v);
#pragma unroll
  for (int off = 1; off < 64; off <<= 1) mx = fmaxf(mx, __shfl_xor(mx, off));
  float l = 0.0f;
  if (lane < nch)      l += wsl[(size_t)row * 128 + lane]      * __expf(m0v - mx);
  if (lane + 64 < nch) l += wsl[(size_t)row * 128 + lane + 64] * __expf(m1v - mx);
#pragma unroll
  for (int off = 1; off < 64; off <<= 1) l += __shfl_xor(l, off);
  if (lane == 0) { Ms[row] = mx; Ls[row] = 1.0f / l; }
}

// ---------------- normalize: out = P * exp(m_chunk - M) * invL (lower), 0 (upper) ----
__global__ __launch_bounds__(256) void normk(const unsigned short* __restrict__ Pb,
                                             float* __restrict__ out,
                                             const float* __restrict__ Ms,
                                             const float* __restrict__ Ls,
                                             const float* __restrict__ wsm) {
  const size_t idx = (size_t)blockIdx.x * 256 + threadIdx.x;  // float4 index
  const int row = (int)(idx >> 11);      // 2048 float4 per row
  const int j0 = (int)(idx & 2047) * 4;
  float4* p = (float4*)out + idx;
  if (j0 > row) {
    float4 z; z.x = 0.f; z.y = 0.f; z.z = 0.f; z.w = 0.f;
    *p = z;
    return;
  }
  const float M = Ms[row];
  const float sc = __expf(wsm[(size_t)row * 128 + (j0 >> 6)] - M) * Ls[row];
  ushort4 q = *(const ushort4*)(Pb + (size_t)row * NR + j0);
  float4 o;
  o.x = bf2f(q.x) * sc;
  o.y = bf2f(q.y) * sc;
  o.z = bf2f(q.z) * sc;
  o.w = bf2f(q.w) * sc;
  if (j0 + 3 > row) {               // boundary quad: zero the masked tail
    if (j0 + 1 > row) o.y = 0.f;
    if (j0 + 2 > row) o.z = 0.f;
    o.w = 0.f;
  }
  *p = o;
}

extern "C" void kernel_launch(void* const* d_in, const int* in_sizes, int n_in,
                              void* d_out, int out_size, void* d_ws, size_t ws_size,
                              hipStream_t stream) {
  const float* x  = (const float*)d_in[0];
  const float* W  = (const float*)d_in[1];
  const float* b  = (const float*)d_in[2];
  const float* rw = (const float*)d_in[3];
  float* out = (float*)d_out;

  char* ws = (char*)d_ws;
  unsigned short* Xb = (unsigned short*)(ws);                        // 16 MB
  unsigned short* Wb = (unsigned short*)(ws + (size_t)(16 << 20));   //  2 MB
  unsigned short* XP = (unsigned short*)(ws + (size_t)(18 << 20));   // 16 MB
  float* wsm = (float*)(ws + (size_t)(34 << 20));                    //  4 MB
  float* wsl = (float*)(ws + (size_t)(38 << 20));                    //  4 MB
  float* Ms  = (float*)(ws + (size_t)(42 << 20));                    // 32 KB
  float* Ls  = (float*)(ws + (size_t)(42 << 20) + 32768);            // 32 KB
  unsigned short* Pb = (unsigned short*)(ws + (size_t)(64 << 20));   // 128 MB bf16 P

  cvt_bf16<<<NR * DIM / 4 / 256, 256, 0, stream>>>(x, Xb, NR * DIM / 4);
  cvt_bf16<<<DIM * DIM / 4 / 256, 256, 0, stream>>>(W, Wb, DIM * DIM / 4);
  gemm1_relu<<<dim3(DIM / 128, NR / 128), 256, 0, stream>>>(Xb, Wb, b, XP);
  gemm2_scores<<<2080, 256, 0, stream>>>(XP, rw, Pb, wsm, wsl);
  rowstats<<<NR / 4, 256, 0, stream>>>(wsm, wsl, Ms, Ls);
  normk<<<(NR / 4) * (NR / 256), 256, 0, stream>>>(Pb, out, Ms, Ls, wsm);
}